// Round 5
// baseline (175.843 us; speedup 1.0000x reference)
//
#include <hip/hip_runtime.h>

#define OUTC 512
#define INC 512
#define SCAN_T 1024
#define NTILE 4
#define TCOL 128   // OUTC / NTILE

typedef __bf16 bf16x8 __attribute__((ext_vector_type(8)));
typedef float f32x4 __attribute__((ext_vector_type(4)));

static __device__ __forceinline__ unsigned short f2bf(float f) {
    unsigned u = __float_as_uint(f);
    unsigned r = u + 0x7fffu + ((u >> 16) & 1u);  // RNE
    return (unsigned short)(r >> 16);
}
static __device__ __forceinline__ float bflo(unsigned r) {
    return __uint_as_float(r << 16);
}
static __device__ __forceinline__ float bfhi(unsigned r) {
    return __uint_as_float(r & 0xffff0000u);
}

// ---------- CSR build ----------
__global__ void k_count(const int* __restrict__ dst, int* __restrict__ counts, int E) {
    int e = blockIdx.x * blockDim.x + threadIdx.x;
    if (e < E) atomicAdd(&counts[dst[e]], 1);
}

__global__ __launch_bounds__(SCAN_T) void k_scan(const int* __restrict__ counts,
                                                 int* __restrict__ row_start,
                                                 int* __restrict__ cursor,
                                                 float* __restrict__ dinv, int N) {
    __shared__ int sums[SCAN_T];
    int t = threadIdx.x;
    int C = (N + SCAN_T - 1) / SCAN_T;
    int lo = t * C;
    int hi = lo + C; if (hi > N) hi = N; if (lo > N) lo = N;
    int s = 0;
    for (int i = lo; i < hi; ++i) s += counts[i];
    sums[t] = s;
    __syncthreads();
    for (int off = 1; off < SCAN_T; off <<= 1) {
        int v = (t >= off) ? sums[t - off] : 0;
        __syncthreads();
        sums[t] += v;
        __syncthreads();
    }
    int run = (t == 0) ? 0 : sums[t - 1];
    for (int i = lo; i < hi; ++i) {
        int c = counts[i];
        row_start[i] = run;
        cursor[i] = run;
        dinv[i] = rsqrtf((float)c + 1.0f);
        run += c;
    }
    if (hi == N) row_start[N] = run;
}

__global__ void k_scatter(const int* __restrict__ src, const int* __restrict__ dst,
                          int* __restrict__ cursor, int* __restrict__ esrc, int E) {
    int e = blockIdx.x * blockDim.x + threadIdx.x;
    if (e < E) {
        int d = dst[e];
        int pos = atomicAdd(&cursor[d], 1);
        esrc[pos] = src[e];
    }
}

// ---------- fused prep: xb convert | W transpose->bf16 | temb ----------
// grid = XBB + 256 + OUTC blocks of 256 threads
__global__ __launch_bounds__(256) void k_prep(const float* __restrict__ x,
                                              const float* __restrict__ W,
                                              const float* __restrict__ t_emb,
                                              const float* __restrict__ Wt,
                                              const float* __restrict__ bt,
                                              const float* __restrict__ b,
                                              unsigned short* __restrict__ xb,
                                              unsigned short* __restrict__ wtb,
                                              float* __restrict__ temb,
                                              int M, int Mpad, int TC, int XBB) {
    __shared__ float smem[32 * 33];
    int bid = blockIdx.x;
    if (bid < XBB) {
        // X -> bf16 (zero-padded rows to Mpad); one thread per 8 elements
        int idx = bid * 256 + threadIdx.x;
        int total = Mpad * (INC / 8);
        if (idx >= total) return;
        int row = idx >> 6;
        int kg = (idx & 63) * 8;
        ushort4 h0 = make_ushort4(0, 0, 0, 0), h1 = make_ushort4(0, 0, 0, 0);
        if (row < M) {
            float4 v0 = *(const float4*)(x + (size_t)row * INC + kg);
            float4 v1 = *(const float4*)(x + (size_t)row * INC + kg + 4);
            h0 = make_ushort4(f2bf(v0.x), f2bf(v0.y), f2bf(v0.z), f2bf(v0.w));
            h1 = make_ushort4(f2bf(v1.x), f2bf(v1.y), f2bf(v1.z), f2bf(v1.w));
        }
        *(ushort4*)(xb + (size_t)row * INC + kg) = h0;
        *(ushort4*)(xb + (size_t)row * INC + kg + 4) = h1;
    } else if (bid < XBB + 256) {
        // W[k][n] -> wtb[n][k] bf16, 32x32 tiles
        int b2 = bid - XBB;
        int bk = (b2 & 15) * 32, bn = (b2 >> 4) * 32;
        int tx = threadIdx.x & 31, ty = threadIdx.x >> 5;  // ty 0..7
        for (int r = ty; r < 32; r += 8)
            smem[r * 33 + tx] = W[(size_t)(bk + r) * OUTC + bn + tx];
        __syncthreads();
        for (int r = ty; r < 32; r += 8)
            wtb[(size_t)(bn + r) * INC + bk + tx] = f2bf(smem[tx * 33 + r]);
    } else {
        // temb[j] = t_emb @ Wt[:,j] + bt[j] + b[j]
        int j = bid - (XBB + 256);
        int t = threadIdx.x;
        float p = 0.0f;
        for (int k = t; k < TC; k += 256) p += t_emb[k] * Wt[(size_t)k * OUTC + j];
        smem[t] = p;
        __syncthreads();
        for (int s = 128; s > 0; s >>= 1) {
            if (t < s) smem[t] += smem[t + s];
            __syncthreads();
        }
        if (t == 0) temb[j] = smem[0] + bt[j] + b[j];
    }
}

// ---------- LDS-free 1-wave MFMA GEMM, register double-buffered K pipeline ----------
// grid (OUTC/64, Mpad/64): n fastest -> blockID%8 == n-tile -> per-XCD wtb residency
// output layout: xwb[tile][Mpad][128] bf16 (column-tiled for the gather)
__global__ __launch_bounds__(64) void k_gemm(const unsigned short* __restrict__ xb,
                                             const unsigned short* __restrict__ wtb,
                                             unsigned short* __restrict__ xwb, int Mpad) {
    const int n0 = blockIdx.x * 64;
    const int m0 = blockIdx.y * 64;
    const int lane = threadIdx.x;
    const int l15 = lane & 15;
    const int k8 = (lane >> 4) * 8;

    const unsigned short* Ab = xb + (size_t)(m0 + l15) * INC + k8;
    const unsigned short* Bb = wtb + (size_t)(n0 + l15) * INC + k8;

    f32x4 acc[4][4];
#pragma unroll
    for (int t = 0; t < 4; ++t)
#pragma unroll
        for (int u = 0; u < 4; ++u)
            acc[t][u] = (f32x4){0.f, 0.f, 0.f, 0.f};

    bf16x8 aA[4], bA[4], aB[4], bB[4];
#pragma unroll
    for (int t = 0; t < 4; ++t) aA[t] = *(const bf16x8*)(Ab + (size_t)t * 16 * INC);
#pragma unroll
    for (int u = 0; u < 4; ++u) bA[u] = *(const bf16x8*)(Bb + (size_t)u * 16 * INC);

#pragma unroll
    for (int k0 = 0; k0 < INC; k0 += 64) {
        const int kn = k0 + 32;
#pragma unroll
        for (int t = 0; t < 4; ++t) aB[t] = *(const bf16x8*)(Ab + (size_t)t * 16 * INC + kn);
#pragma unroll
        for (int u = 0; u < 4; ++u) bB[u] = *(const bf16x8*)(Bb + (size_t)u * 16 * INC + kn);
#pragma unroll
        for (int u = 0; u < 4; ++u)
#pragma unroll
            for (int t = 0; t < 4; ++t)
                acc[t][u] = __builtin_amdgcn_mfma_f32_16x16x32_bf16(aA[t], bA[u], acc[t][u], 0, 0, 0);
        const int kn2 = (k0 + 64 < INC) ? k0 + 64 : 0;  // dummy reload on last iter
#pragma unroll
        for (int t = 0; t < 4; ++t) aA[t] = *(const bf16x8*)(Ab + (size_t)t * 16 * INC + kn2);
#pragma unroll
        for (int u = 0; u < 4; ++u) bA[u] = *(const bf16x8*)(Bb + (size_t)u * 16 * INC + kn2);
#pragma unroll
        for (int u = 0; u < 4; ++u)
#pragma unroll
            for (int t = 0; t < 4; ++t)
                acc[t][u] = __builtin_amdgcn_mfma_f32_16x16x32_bf16(aB[t], bB[u], acc[t][u], 0, 0, 0);
    }

    const int rbase = (lane >> 4) * 4;
#pragma unroll
    for (int t = 0; t < 4; ++t)
#pragma unroll
        for (int u = 0; u < 4; ++u) {
            int gcol = n0 + u * 16 + l15;
            unsigned short* p = xwb + (size_t)(gcol >> 7) * Mpad * TCOL + (gcol & 127);
#pragma unroll
            for (int r = 0; r < 4; ++r) {
                int grow = m0 + t * 16 + rbase + r;  // < Mpad (padded)
                p[(size_t)grow * TCOL] = f2bf(acc[t][u][r]);
            }
        }
}

// ---------- column-tiled CSR gather: wave=node, lane=2 cols, tile slow axis ----------
__global__ __launch_bounds__(256) void k_gather(const int* __restrict__ esrc,
                                                const int* __restrict__ row_start,
                                                const unsigned short* __restrict__ XWT,
                                                const float* __restrict__ dinv,
                                                const float* __restrict__ temb,
                                                float* __restrict__ out, int N, int Mpad) {
    const int tile = blockIdx.y;
    const int node = blockIdx.x * 4 + (threadIdx.x >> 6);
    if (node >= N) return;
    const int lane = threadIdx.x & 63;
    const int c2 = lane * 2;
    const unsigned short* base = XWT + (size_t)tile * Mpad * TCOL + c2;
    const int gc = tile * TCOL + c2;

    const float di = dinv[node];
    float a0, a1;
    {
        unsigned r = *(const unsigned*)(base + (size_t)node * TCOL);
        float2 tv = *(const float2*)(temb + gc);
        float nd = di * di;
        a0 = tv.x + nd * bflo(r);
        a1 = tv.y + nd * bfhi(r);
    }

    const int s0 = row_start[node];
    const int s1 = row_start[node + 1];
    int i = s0;
    for (; i + 4 <= s1; i += 4) {
        int s[4]; float nn[4]; unsigned rr[4];
#pragma unroll
        for (int j = 0; j < 4; ++j) s[j] = esrc[i + j];
#pragma unroll
        for (int j = 0; j < 4; ++j) nn[j] = dinv[s[j]] * di;
#pragma unroll
        for (int j = 0; j < 4; ++j) rr[j] = *(const unsigned*)(base + (size_t)s[j] * TCOL);
#pragma unroll
        for (int j = 0; j < 4; ++j) {
            a0 += nn[j] * bflo(rr[j]);
            a1 += nn[j] * bfhi(rr[j]);
        }
    }
    for (; i < s1; ++i) {
        int s = esrc[i];
        float nrm = dinv[s] * di;
        unsigned r = *(const unsigned*)(base + (size_t)s * TCOL);
        a0 += nrm * bflo(r);
        a1 += nrm * bfhi(r);
    }

    *(float2*)(out + (size_t)node * OUTC + gc) = make_float2(a0, a1);
}

extern "C" void kernel_launch(void* const* d_in, const int* in_sizes, int n_in,
                              void* d_out, int out_size, void* d_ws, size_t ws_size,
                              hipStream_t stream) {
    const float* x     = (const float*)d_in[0];
    const float* t_emb = (const float*)d_in[1];
    const int*   ei    = (const int*)d_in[2];
    const float* W     = (const float*)d_in[3];
    const float* b     = (const float*)d_in[4];
    const float* Wt    = (const float*)d_in[5];
    const float* bt    = (const float*)d_in[6];
    float* out = (float*)d_out;

    const int N  = in_sizes[0] / INC;   // 10000
    const int E  = in_sizes[2] / 2;     // 160000
    const int TC = in_sizes[1];         // 256
    const int Mpad = (N + 63) & ~63;    // 10048

    char* ws = (char*)d_ws;
    size_t off = 0;
    unsigned short* xb  = (unsigned short*)(ws + off); off += (size_t)Mpad * INC * 2;
    unsigned short* xwb = (unsigned short*)(ws + off); off += (size_t)Mpad * OUTC * 2;
    unsigned short* wtb = (unsigned short*)(ws + off); off += (size_t)INC * OUTC * 2;
    float* dinv = (float*)(ws + off);      off += ((size_t)N * 4 + 255) & ~(size_t)255;
    int* counts = (int*)(ws + off);        off += ((size_t)N * 4 + 255) & ~(size_t)255;
    int* row_start = (int*)(ws + off);     off += ((size_t)(N + 1) * 4 + 255) & ~(size_t)255;
    int* cursor = (int*)(ws + off);        off += ((size_t)N * 4 + 255) & ~(size_t)255;
    int* esrc = (int*)(ws + off);          off += ((size_t)E * 4 + 255) & ~(size_t)255;
    float* temb = (float*)(ws + off);      off += OUTC * 4;

    const int* srcIdx = ei;
    const int* dstIdx = ei + E;

    const int XBB = (Mpad * (INC / 8) + 255) / 256;  // xb-convert blocks

    hipMemsetAsync(counts, 0, (size_t)N * sizeof(int), stream);
    k_count<<<(E + 255) / 256, 256, 0, stream>>>(dstIdx, counts, E);
    k_scan<<<1, SCAN_T, 0, stream>>>(counts, row_start, cursor, dinv, N);
    k_scatter<<<(E + 255) / 256, 256, 0, stream>>>(srcIdx, dstIdx, cursor, esrc, E);
    k_prep<<<XBB + 256 + OUTC, 256, 0, stream>>>(x, W, t_emb, Wt, bt, b,
                                                 xb, wtb, temb, N, Mpad, TC, XBB);

    dim3 gemm_grid(OUTC / 64, Mpad / 64);  // n fastest -> XCD-stable n-tiles
    k_gemm<<<gemm_grid, 64, 0, stream>>>(xb, wtb, xwb, Mpad);

    dim3 gather_grid((N + 3) / 4, NTILE);  // tile on slow axis
    k_gather<<<gather_grid, 256, 0, stream>>>(esrc, row_start, xwb, dinv, temb, out, N, Mpad);
}